// Round 1
// baseline (813.234 us; speedup 1.0000x reference)
//
#include <hip/hip_runtime.h>
#include <hip/hip_fp16.h>

#define T_STEPS 512
#define B_ENV   256
#define D_IN    64
#define H_DIM   128
#define G4      (4*H_DIM)   // 512 gate rows

typedef _Float16 h2v __attribute__((ext_vector_type(2)));

__device__ __forceinline__ float dot2(h2v a, h2v b, float c) {
#if __has_builtin(__builtin_amdgcn_fdot2)
    return __builtin_amdgcn_fdot2(a, b, c, false);
#else
    return c + (float)a.x * (float)b.x + (float)a.y * (float)b.y;
#endif
}

__device__ __forceinline__ float fast_rcp(float x) {
#if __has_builtin(__builtin_amdgcn_rcpf)
    return __builtin_amdgcn_rcpf(x);
#else
    return 1.0f / x;
#endif
}

// sigmoid(x) = 1/(1+e^-x); handles +-inf correctly via rcp(inf)=0
__device__ __forceinline__ float sigm(float x) {
    return fast_rcp(1.0f + __expf(-x));
}
// tanh(x) = 1 - 2/(e^{2x}+1); e=inf -> 1, e=0 -> -1  (no NaN at extremes)
__device__ __forceinline__ float tanh_f(float x) {
    float e = __expf(2.0f * x);
    return 1.0f - 2.0f * fast_rcp(e + 1.0f);
}

// One block per environment (B=256 blocks -> one per CU).
// 1024 threads: tid = rg*8 + k8. rg in [0,128): owns 4 gate rows (rg*4..+3)
// for the gate matvec, and out-row rg for the hidden projection.
// k8 in [0,8): 8-way k-split of the dot products, reduced via shfl_xor.
__global__ __launch_bounds__(1024, 4)
void ppo_lstm_scan(const float* __restrict__ x,      // [T,B,D]
                   const float* __restrict__ done,   // [T,B]
                   const float* __restrict__ h0,     // [B,H]
                   const float* __restrict__ c0,     // [B,H]
                   const float* __restrict__ W_ih,   // [4H,D]
                   const float* __restrict__ b_ih,   // [4H]
                   const float* __restrict__ W_hh,   // [4H,H]
                   const float* __restrict__ b_hh,   // [4H]
                   const float* __restrict__ W_hid,  // [H,H]
                   const float* __restrict__ b_hid,  // [H]
                   float* __restrict__ out)          // [T*B,H]
{
    const int b   = blockIdx.x;
    const int tid = threadIdx.x;
    const int k8  = tid & 7;
    const int rg  = tid >> 3;   // 0..127

    __shared__ h2v   h_lds[H_DIM/2];  // h_t as f16 pairs
    __shared__ h2v   x_lds[D_IN/2];   // x_t as f16 pairs
    __shared__ float c_lds[H_DIM];    // cell state, f32
    __shared__ float g_lds[G4];       // raw gates -> activated in place

    // ---- load per-thread weight slices into registers (one-time) ----
    h2v whh[4][8];   // rows rg*4+i, cols k8*16 + 2c (+1)
    h2v wih[4][4];   // rows rg*4+i, cols k8*8 + 2c (+1)
    h2v whid[8];     // row rg, cols k8*16 + 2c (+1)
    float bias[4];
    #pragma unroll
    for (int i = 0; i < 4; ++i) {
        const int r = rg*4 + i;
        const float* wr = W_hh + r*H_DIM + k8*16;
        #pragma unroll
        for (int c2 = 0; c2 < 8; ++c2) {
            h2v p; p.x = (_Float16)wr[2*c2]; p.y = (_Float16)wr[2*c2+1];
            whh[i][c2] = p;
        }
        const float* wr2 = W_ih + r*D_IN + k8*8;
        #pragma unroll
        for (int c2 = 0; c2 < 4; ++c2) {
            h2v p; p.x = (_Float16)wr2[2*c2]; p.y = (_Float16)wr2[2*c2+1];
            wih[i][c2] = p;
        }
        bias[i] = b_ih[r] + b_hh[r];
    }
    {
        const float* wp = W_hid + rg*H_DIM + k8*16;
        #pragma unroll
        for (int c2 = 0; c2 < 8; ++c2) {
            h2v p; p.x = (_Float16)wp[2*c2]; p.y = (_Float16)wp[2*c2+1];
            whid[c2] = p;
        }
    }
    const float bh = b_hid[rg];

    // ---- stage h0, c0, x_0 ----
    if (tid < 64) {
        float2 v = *reinterpret_cast<const float2*>(h0 + b*H_DIM + 2*tid);
        h2v p; p.x = (_Float16)v.x; p.y = (_Float16)v.y;
        h_lds[tid] = p;
    } else if (tid < 128) {
        const int j = tid - 64;
        float2 v = *reinterpret_cast<const float2*>(c0 + b*H_DIM + 2*j);
        c_lds[2*j] = v.x; c_lds[2*j+1] = v.y;
    } else if (tid < 160) {
        const int j = tid - 128;
        float2 v = *reinterpret_cast<const float2*>(x + (size_t)b*D_IN + 2*j);
        h2v p; p.x = (_Float16)v.x; p.y = (_Float16)v.y;
        x_lds[j] = p;
    }
    __syncthreads();

    for (int t = 0; t < T_STEPS; ++t) {
        const float mask = 1.0f - done[t*B_ENV + b];

        // ---- P1: gate matvec (+ projection of h_{t-1} for out row t-1) ----
        h2v hv[8];
        #pragma unroll
        for (int c2 = 0; c2 < 8; ++c2) hv[c2] = h_lds[k8*8 + c2];
        h2v xv[4];
        #pragma unroll
        for (int c2 = 0; c2 < 4; ++c2) xv[c2] = x_lds[k8*4 + c2];

        float gh[4] = {0.f,0.f,0.f,0.f};
        float gx[4] = {0.f,0.f,0.f,0.f};
        #pragma unroll
        for (int i = 0; i < 4; ++i) {
            #pragma unroll
            for (int c2 = 0; c2 < 8; ++c2) gh[i] = dot2(whh[i][c2], hv[c2], gh[i]);
            #pragma unroll
            for (int c2 = 0; c2 < 4; ++c2) gx[i] = dot2(wih[i][c2], xv[c2], gx[i]);
        }
        float po = 0.f;
        if (t > 0) {
            #pragma unroll
            for (int c2 = 0; c2 < 8; ++c2) po = dot2(whid[c2], hv[c2], po);
        }
        float gs[4];
        #pragma unroll
        for (int i = 0; i < 4; ++i) gs[i] = gx[i] + mask * gh[i] + bias[i];

        #pragma unroll
        for (int m = 1; m <= 4; m <<= 1) {
            #pragma unroll
            for (int i = 0; i < 4; ++i) gs[i] += __shfl_xor(gs[i], m, 64);
            po += __shfl_xor(po, m, 64);
        }
        if (k8 == 0) {
            float4 w; w.x = gs[0]; w.y = gs[1]; w.z = gs[2]; w.w = gs[3];
            *reinterpret_cast<float4*>(&g_lds[rg*4]) = w;   // rows rg*4..+3
            if (t > 0)
                out[(size_t)(t-1)*B_ENV*H_DIM + (size_t)b*H_DIM + rg] = po + bh;
        }
        __syncthreads();

        // ---- P2: activations in place (512 threads) ----
        if (tid < G4) {
            float v = g_lds[tid];
            g_lds[tid] = ((tid >> 7) == 2) ? tanh_f(v) : sigm(v);
        }
        __syncthreads();

        // ---- P3: cell update (128 threads) + stage x_{t+1} (32 threads) ----
        if (tid < H_DIM) {
            const int j = tid;
            float pi  = g_lds[j];
            float pf  = g_lds[H_DIM + j];
            float pg  = g_lds[2*H_DIM + j];
            float pou = g_lds[3*H_DIM + j];
            float cn  = pf * c_lds[j] * mask + pi * pg;
            c_lds[j]  = cn;
            float hn  = pou * tanh_f(cn);
            reinterpret_cast<_Float16*>(h_lds)[j] = (_Float16)hn;
        } else if (tid < 160 && (t + 1) < T_STEPS) {
            const int j = tid - 128;
            float2 v = *reinterpret_cast<const float2*>(
                x + (size_t)(t+1)*B_ENV*D_IN + (size_t)b*D_IN + 2*j);
            h2v p; p.x = (_Float16)v.x; p.y = (_Float16)v.y;
            x_lds[j] = p;
        }
        __syncthreads();
    }

    // ---- epilogue: projection of h_{T-1} -> out row T-1 ----
    {
        h2v hv[8];
        #pragma unroll
        for (int c2 = 0; c2 < 8; ++c2) hv[c2] = h_lds[k8*8 + c2];
        float po = 0.f;
        #pragma unroll
        for (int c2 = 0; c2 < 8; ++c2) po = dot2(whid[c2], hv[c2], po);
        #pragma unroll
        for (int m = 1; m <= 4; m <<= 1) po += __shfl_xor(po, m, 64);
        if (k8 == 0)
            out[(size_t)(T_STEPS-1)*B_ENV*H_DIM + (size_t)b*H_DIM + rg] = po + bh;
    }
}

extern "C" void kernel_launch(void* const* d_in, const int* in_sizes, int n_in,
                              void* d_out, int out_size, void* d_ws, size_t ws_size,
                              hipStream_t stream) {
    const float* x     = (const float*)d_in[0];
    const float* done  = (const float*)d_in[1];
    const float* h0    = (const float*)d_in[2];
    const float* c0    = (const float*)d_in[3];
    const float* W_ih  = (const float*)d_in[4];
    const float* b_ih  = (const float*)d_in[5];
    const float* W_hh  = (const float*)d_in[6];
    const float* b_hh  = (const float*)d_in[7];
    const float* W_hid = (const float*)d_in[8];
    const float* b_hid = (const float*)d_in[9];
    float* out = (float*)d_out;

    hipLaunchKernelGGL(ppo_lstm_scan, dim3(B_ENV), dim3(1024), 0, stream,
                       x, done, h0, c0, W_ih, b_ih, W_hh, b_hh, W_hid, b_hid, out);
}